// Round 7
// baseline (1011.563 us; speedup 1.0000x reference)
//
#include <hip/hip_runtime.h>
#include <hip/hip_bf16.h>

// G2-GCN fused pipeline for MI355X — round 7.
// vs round 6 (verified): gate + energy gathers switch to bf16 rows (128B/row:
// half the 64B sectors per random row, and the 6.4MB array largely fits the
// per-XCD 4MB L2). The main agg path stays fp32 (feeds x directly).
// Error budget: tau bias ~1e-5 rel; energy bias ~2e2 absolute vs 3e5 threshold.

#define N_NODES 50000
#define N_EDGES 800000
#define N_GRAPH 500
#define N_LAYERS 4
#define HDIM 64
#define DDIN 128
#define BN_EPS 1e-5f
#define NEPART 256
#define SC_CHUNK 2048
#define SC_NBLK ((N_NODES + SC_CHUNK - 1) / SC_CHUNK)  // 25
#define NPARTS 8
#define PRNG (N_NODES / NPARTS)  // 6250 exactly
#define FILL_BPP 56              // blocks per partition in partitioned kernels

typedef __hip_bfloat16 bf16;

// ---------------- CSR build ----------------

// XCD-partitioned degree count (verified r6): block-group (blockIdx&7) owns a
// node range; all atomics for a counter line come from ONE XCD -> L2-local.
__global__ __launch_bounds__(256) void k_degrees(const int* __restrict__ ei,
                                                 int* __restrict__ deg_in,
                                                 int* __restrict__ deg_out) {
  int part = blockIdx.x & (NPARTS - 1);
  int slice = blockIdx.x >> 3;
  int nslice = gridDim.x >> 3;
  int lo = part * PRNG, hi = lo + PRNG;
  int stride = nslice * 256;
  for (int e = slice * 256 + threadIdx.x; e < N_EDGES; e += stride) {
    int s = ei[e], d = ei[N_EDGES + e];
    if (s >= lo && s < hi) atomicAdd(&deg_out[s], 1);
    if (d >= lo && d < hi) atomicAdd(&deg_in[d], 1);
  }
}

// phase 1: per-block local exclusive scan (2048 elems) + block sums.
__global__ __launch_bounds__(256) void k_scan1(const int* __restrict__ deg_in,
                                               const int* __restrict__ deg_out,
                                               int* __restrict__ rp_dst,
                                               int* __restrict__ rp_src,
                                               int* __restrict__ bsum) {
  int arr = blockIdx.y;
  const int* in = arr ? deg_out : deg_in;
  int* out = arr ? rp_src : rp_dst;
  int base = blockIdx.x * SC_CHUNK + threadIdx.x * 8;
  int v[8];
  int s = 0;
#pragma unroll
  for (int j = 0; j < 8; ++j) {
    int ii = base + j;
    v[j] = (ii < N_NODES) ? in[ii] : 0;
    s += v[j];
  }
  __shared__ int sh[256];
  sh[threadIdx.x] = s;
  __syncthreads();
  for (int off = 1; off < 256; off <<= 1) {
    int t = (threadIdx.x >= off) ? sh[threadIdx.x - off] : 0;
    __syncthreads();
    sh[threadIdx.x] += t;
    __syncthreads();
  }
  int run = sh[threadIdx.x] - s;
#pragma unroll
  for (int j = 0; j < 8; ++j) {
    int ii = base + j;
    if (ii < N_NODES) out[ii] = run;
    run += v[j];
  }
  if (threadIdx.x == 255) bsum[arr * SC_NBLK + blockIdx.x] = sh[255];
}

// phase 2: scan the block sums (one wave), set rp[N]=E.
__global__ __launch_bounds__(64) void k_scan2(const int* __restrict__ bsum,
                                              int* __restrict__ boff,
                                              int* __restrict__ rp_dst,
                                              int* __restrict__ rp_src) {
  int lane = threadIdx.x;
  for (int a = 0; a < 2; ++a) {
    int v = (lane < SC_NBLK) ? bsum[a * SC_NBLK + lane] : 0;
    int incl = v;
    for (int off = 1; off < 64; off <<= 1) {
      int t = __shfl_up(incl, off);
      if (lane >= off) incl += t;
    }
    if (lane < SC_NBLK) boff[a * SC_NBLK + lane] = incl - v;
  }
  if (lane == 0) {
    rp_dst[N_NODES] = N_EDGES;
    rp_src[N_NODES] = N_EDGES;
  }
}

// phase 3: add block offsets, write cursor copies; fuse dinv (arr 0).
__global__ __launch_bounds__(256) void k_scan3(const int* __restrict__ boff,
                                               int* __restrict__ rp_dst,
                                               int* __restrict__ rp_src,
                                               int* __restrict__ cur_dst,
                                               int* __restrict__ cur_src,
                                               const int* __restrict__ deg_in,
                                               float* __restrict__ dinv) {
  int arr = blockIdx.y;
  int* rp = arr ? rp_src : rp_dst;
  int* cur = arr ? cur_src : cur_dst;
  int off = boff[arr * SC_NBLK + blockIdx.x];
  int base = blockIdx.x * SC_CHUNK + threadIdx.x * 8;
#pragma unroll
  for (int j = 0; j < 8; ++j) {
    int ii = base + j;
    if (ii < N_NODES) {
      int v = rp[ii] + off;
      rp[ii] = v;
      cur[ii] = v;
      if (arr == 0) dinv[ii] = rsqrtf((float)(deg_in[ii] + 1));  // + self loop
    }
  }
}

// XCD-partitioned fill (verified r6): CSR lines dirtied by a single XCD only.
__global__ __launch_bounds__(256) void k_fill(const int* __restrict__ ei,
                                              int* __restrict__ cur_dst,
                                              int* __restrict__ cur_src,
                                              int* __restrict__ csr_dst,
                                              int* __restrict__ csr_src) {
  int part = blockIdx.x & (NPARTS - 1);
  int slice = blockIdx.x >> 3;
  int nslice = gridDim.x >> 3;
  int lo = part * PRNG, hi = lo + PRNG;
  int stride = nslice * 256;
  for (int e = slice * 256 + threadIdx.x; e < N_EDGES; e += stride) {
    int s = ei[e], d = ei[N_EDGES + e];
    if (d >= lo && d < hi) {
      int q = atomicAdd(&cur_dst[d], 1);
      csr_dst[q] = s;  // source node for dst-gather
    }
    if (s >= lo && s < hi) {
      int q = atomicAdd(&cur_src[s], 1);
      csr_src[q] = d;  // dest node for src-gather
    }
  }
}

// ---------------- dense kernels ----------------

__global__ __launch_bounds__(256) void k_prelin(const float* __restrict__ x0,
                                                const float* __restrict__ W,
                                                const float* __restrict__ b,
                                                float* __restrict__ x) {
  __shared__ float Ws[DDIN * HDIM];  // 32 KB
  for (int t = threadIdx.x; t < DDIN * HDIM; t += 256) Ws[t] = W[t];
  __syncthreads();
  int wave = threadIdx.x >> 6, lane = threadIdx.x & 63;
  float bias = b[lane];
  int stride = gridDim.x * 4;
  for (int i = blockIdx.x * 4 + wave; i < N_NODES; i += stride) {
    const float* xr = x0 + (size_t)i * DDIN;
    float xl0 = xr[lane], xl1 = xr[64 + lane];
    float acc = bias;
#pragma unroll
    for (int k = 0; k < 64; ++k) acc = fmaf(__shfl(xl0, k), Ws[k * 64 + lane], acc);
#pragma unroll
    for (int k = 0; k < 64; ++k) acc = fmaf(__shfl(xl1, k), Ws[(64 + k) * 64 + lane], acc);
    x[(size_t)i * HDIM + lane] = fmaxf(acc, 0.f);
  }
}

// ---------------- fused gather + dual GEMM (one wave per node) ----------------
// acc = dinv[i]*(x[i]*dinv[i] + sum_in x[s]*dinv[s]);
// x_ = relu(acc@W1+b1) [fp32], Xch = relu(acc@W2+b2) [bf16, gate input only].
__global__ __launch_bounds__(256) void k_agg_gemm(const float* __restrict__ x,
                                                  const int* __restrict__ rp,
                                                  const int* __restrict__ csr,
                                                  const float* __restrict__ dinv,
                                                  const float* __restrict__ W1,
                                                  const float* __restrict__ W2,
                                                  const float* __restrict__ b1,
                                                  const float* __restrict__ b2,
                                                  float* __restrict__ x_,
                                                  bf16* __restrict__ Xch) {
  __shared__ float W1s[HDIM * HDIM], W2s[HDIM * HDIM];
  for (int t = threadIdx.x; t < HDIM * HDIM; t += 256) {
    W1s[t] = W1[t];
    W2s[t] = W2[t];
  }
  __syncthreads();
  int wave = threadIdx.x >> 6, lane = threadIdx.x & 63;
  float bb1 = b1[lane], bb2 = b2[lane];
  int stride = gridDim.x * 4;
  for (int i = blockIdx.x * 4 + wave; i < N_NODES; i += stride) {
    int e0 = rp[i], e1 = rp[i + 1];
    float di = dinv[i];
    size_t li = (size_t)i * HDIM + lane;
    float a0 = x[li] * di, a1 = 0.f, a2 = 0.f, a3 = 0.f;  // self loop in a0
    for (int base = e0; base < e1; base += 64) {
      int m = e1 - base;
      if (m > 64) m = 64;
      int idx = csr[base + (lane < m ? lane : 0)];
      float dv = dinv[idx];
      int k = 0;
      for (; k + 8 <= m; k += 8) {
        int s0 = __shfl(idx, k), s1 = __shfl(idx, k + 1), s2 = __shfl(idx, k + 2),
            s3 = __shfl(idx, k + 3), s4 = __shfl(idx, k + 4), s5 = __shfl(idx, k + 5),
            s6 = __shfl(idx, k + 6), s7 = __shfl(idx, k + 7);
        float w0 = __shfl(dv, k), w1 = __shfl(dv, k + 1), w2 = __shfl(dv, k + 2),
              w3 = __shfl(dv, k + 3), w4 = __shfl(dv, k + 4), w5 = __shfl(dv, k + 5),
              w6 = __shfl(dv, k + 6), w7 = __shfl(dv, k + 7);
        float v0 = x[(size_t)s0 * HDIM + lane], v1 = x[(size_t)s1 * HDIM + lane];
        float v2 = x[(size_t)s2 * HDIM + lane], v3 = x[(size_t)s3 * HDIM + lane];
        float v4 = x[(size_t)s4 * HDIM + lane], v5 = x[(size_t)s5 * HDIM + lane];
        float v6 = x[(size_t)s6 * HDIM + lane], v7 = x[(size_t)s7 * HDIM + lane];
        a0 = fmaf(v0, w0, a0);
        a1 = fmaf(v1, w1, a1);
        a2 = fmaf(v2, w2, a2);
        a3 = fmaf(v3, w3, a3);
        a0 = fmaf(v4, w4, a0);
        a1 = fmaf(v5, w5, a1);
        a2 = fmaf(v6, w6, a2);
        a3 = fmaf(v7, w7, a3);
      }
      for (; k < m; ++k) {
        int s = __shfl(idx, k);
        float w = __shfl(dv, k);
        a0 = fmaf(x[(size_t)s * HDIM + lane], w, a0);
      }
    }
    float acc = (a0 + a1 + a2 + a3) * di;
    float r1 = 0.f, r2 = 0.f;
#pragma unroll
    for (int k = 0; k < 64; ++k) {
      float xv = __shfl(acc, k);
      r1 = fmaf(xv, W1s[k * 64 + lane], r1);
      r2 = fmaf(xv, W2s[k * 64 + lane], r2);
    }
    x_[li] = fmaxf(r1 + bb1, 0.f);
    Xch[li] = __float2bfloat16(fmaxf(r2 + bb2, 0.f));
  }
}

// tau = tanh(mean_over_out_edges (Xc[i]-Xc[d])^2) on bf16 rows;
// x = (1-tau)*x + tau*x_ ; also emit bf16 copy of new x for the energy pass.
__global__ __launch_bounds__(256) void k_gate(const bf16* __restrict__ Xch,
                                              const float* __restrict__ x_,
                                              const int* __restrict__ rp,
                                              const int* __restrict__ csr,
                                              float* __restrict__ x,
                                              bf16* __restrict__ xh) {
  int i = (blockIdx.x * 256 + threadIdx.x) >> 6;
  int lane = threadIdx.x & 63;
  if (i >= N_NODES) return;
  int e0 = rp[i], e1 = rp[i + 1];
  float xi = __bfloat162float(Xch[(size_t)i * HDIM + lane]);
  float a0 = 0.f, a1 = 0.f, a2 = 0.f, a3 = 0.f;
  for (int base = e0; base < e1; base += 64) {
    int m = e1 - base;
    if (m > 64) m = 64;
    int idx = csr[base + (lane < m ? lane : 0)];
    int k = 0;
    for (; k + 8 <= m; k += 8) {
      int s0 = __shfl(idx, k), s1 = __shfl(idx, k + 1), s2 = __shfl(idx, k + 2),
          s3 = __shfl(idx, k + 3), s4 = __shfl(idx, k + 4), s5 = __shfl(idx, k + 5),
          s6 = __shfl(idx, k + 6), s7 = __shfl(idx, k + 7);
      float v0 = __bfloat162float(Xch[(size_t)s0 * HDIM + lane]);
      float v1 = __bfloat162float(Xch[(size_t)s1 * HDIM + lane]);
      float v2 = __bfloat162float(Xch[(size_t)s2 * HDIM + lane]);
      float v3 = __bfloat162float(Xch[(size_t)s3 * HDIM + lane]);
      float v4 = __bfloat162float(Xch[(size_t)s4 * HDIM + lane]);
      float v5 = __bfloat162float(Xch[(size_t)s5 * HDIM + lane]);
      float v6 = __bfloat162float(Xch[(size_t)s6 * HDIM + lane]);
      float v7 = __bfloat162float(Xch[(size_t)s7 * HDIM + lane]);
      float t0 = xi - v0, t1 = xi - v1, t2 = xi - v2, t3 = xi - v3;
      float t4 = xi - v4, t5 = xi - v5, t6 = xi - v6, t7 = xi - v7;
      a0 = fmaf(t0, t0, a0);
      a1 = fmaf(t1, t1, a1);
      a2 = fmaf(t2, t2, a2);
      a3 = fmaf(t3, t3, a3);
      a0 = fmaf(t4, t4, a0);
      a1 = fmaf(t5, t5, a1);
      a2 = fmaf(t6, t6, a2);
      a3 = fmaf(t7, t7, a3);
    }
    for (; k < m; ++k) {
      int d = __shfl(idx, k);
      float t = xi - __bfloat162float(Xch[(size_t)d * HDIM + lane]);
      a0 = fmaf(t, t, a0);
    }
  }
  int cnt = e1 - e0;
  float tau = tanhf((a0 + a1 + a2 + a3) / (float)(cnt > 0 ? cnt : 1));
  size_t idx = (size_t)i * HDIM + lane;
  float xn = (1.f - tau) * x[idx] + tau * x_[idx];
  x[idx] = xn;
  xh[idx] = __float2bfloat16(xn);
}

// energy partials (grouped by src, bf16 rows) + global add pool (fp32), fused.
__global__ __launch_bounds__(256) void k_epool(const float* __restrict__ x,
                                               const bf16* __restrict__ xh,
                                               const int* __restrict__ rp,
                                               const int* __restrict__ csr,
                                               const int* __restrict__ batch,
                                               float* __restrict__ hpool,
                                               float* __restrict__ epart) {
  int i = (blockIdx.x * 256 + threadIdx.x) >> 6;
  int lane = threadIdx.x & 63;
  if (i >= N_NODES) return;
  size_t li = (size_t)i * HDIM + lane;
  float xi = __bfloat162float(xh[li]);  // symmetric rounding vs gathered rows
  int e0 = rp[i], e1 = rp[i + 1];
  float a0 = 0.f, a1 = 0.f, a2 = 0.f, a3 = 0.f;
  for (int base = e0; base < e1; base += 64) {
    int m = e1 - base;
    if (m > 64) m = 64;
    int idx = csr[base + (lane < m ? lane : 0)];
    int k = 0;
    for (; k + 8 <= m; k += 8) {
      int s0 = __shfl(idx, k), s1 = __shfl(idx, k + 1), s2 = __shfl(idx, k + 2),
          s3 = __shfl(idx, k + 3), s4 = __shfl(idx, k + 4), s5 = __shfl(idx, k + 5),
          s6 = __shfl(idx, k + 6), s7 = __shfl(idx, k + 7);
      float v0 = __bfloat162float(xh[(size_t)s0 * HDIM + lane]);
      float v1 = __bfloat162float(xh[(size_t)s1 * HDIM + lane]);
      float v2 = __bfloat162float(xh[(size_t)s2 * HDIM + lane]);
      float v3 = __bfloat162float(xh[(size_t)s3 * HDIM + lane]);
      float v4 = __bfloat162float(xh[(size_t)s4 * HDIM + lane]);
      float v5 = __bfloat162float(xh[(size_t)s5 * HDIM + lane]);
      float v6 = __bfloat162float(xh[(size_t)s6 * HDIM + lane]);
      float v7 = __bfloat162float(xh[(size_t)s7 * HDIM + lane]);
      float t0 = xi - v0, t1 = xi - v1, t2 = xi - v2, t3 = xi - v3;
      float t4 = xi - v4, t5 = xi - v5, t6 = xi - v6, t7 = xi - v7;
      a0 = fmaf(t0, t0, a0);
      a1 = fmaf(t1, t1, a1);
      a2 = fmaf(t2, t2, a2);
      a3 = fmaf(t3, t3, a3);
      a0 = fmaf(t4, t4, a0);
      a1 = fmaf(t5, t5, a1);
      a2 = fmaf(t6, t6, a2);
      a3 = fmaf(t7, t7, a3);
    }
    for (; k < m; ++k) {
      int d = __shfl(idx, k);
      float t = xi - __bfloat162float(xh[(size_t)d * HDIM + lane]);
      a0 = fmaf(t, t, a0);
    }
  }
  int g = batch[i];  // wave-uniform
  atomicAdd(&hpool[g * HDIM + lane], x[li]);  // exact fp32 pool
  float acc = a0 + a1 + a2 + a3;
  acc += __shfl_down(acc, 32);
  acc += __shfl_down(acc, 16);
  acc += __shfl_down(acc, 8);
  acc += __shfl_down(acc, 4);
  acc += __shfl_down(acc, 2);
  acc += __shfl_down(acc, 1);
  if (lane == 0) atomicAdd(&epart[i & (NEPART - 1)], acc);
}

__global__ __launch_bounds__(256) void k_esum(const float* __restrict__ epart,
                                              float* __restrict__ out_e) {
  __shared__ float sh[NEPART];
  int t = threadIdx.x;
  sh[t] = epart[t];
  __syncthreads();
  for (int off = NEPART / 2; off > 0; off >>= 1) {
    if (t < off) sh[t] += sh[t + off];
    __syncthreads();
  }
  if (t == 0) out_e[0] = 0.5f * sh[0];
}

// ---------------- readout MLP (fused GEMM + BN + relu, one block per column) --

__global__ __launch_bounds__(256) void k_mlpbn(const float* __restrict__ Hin,
                                               const float* __restrict__ W,
                                               const float* __restrict__ b,
                                               const float* __restrict__ g,
                                               const float* __restrict__ bb,
                                               float* __restrict__ Z) {
  int c = blockIdx.x;
  __shared__ float Wc[HDIM];
  __shared__ float red[256];
  if (threadIdx.x < HDIM) Wc[threadIdx.x] = W[threadIdx.x * HDIM + c];
  __syncthreads();
  int r0 = threadIdx.x, r1 = threadIdx.x + 256;
  float bc = b[c];
  float d0 = bc, d1 = bc;
  if (r0 < N_GRAPH) {
    const float* h = Hin + (size_t)r0 * HDIM;
#pragma unroll
    for (int k = 0; k < HDIM; ++k) d0 = fmaf(h[k], Wc[k], d0);
  }
  if (r1 < N_GRAPH) {
    const float* h = Hin + (size_t)r1 * HDIM;
#pragma unroll
    for (int k = 0; k < HDIM; ++k) d1 = fmaf(h[k], Wc[k], d1);
  }
  red[threadIdx.x] = (r0 < N_GRAPH ? d0 : 0.f) + (r1 < N_GRAPH ? d1 : 0.f);
  __syncthreads();
  for (int off = 128; off > 0; off >>= 1) {
    if (threadIdx.x < off) red[threadIdx.x] += red[threadIdx.x + off];
    __syncthreads();
  }
  float mean = red[0] / (float)N_GRAPH;
  __syncthreads();
  float t0 = (r0 < N_GRAPH) ? d0 - mean : 0.f;
  float t1 = (r1 < N_GRAPH) ? d1 - mean : 0.f;
  red[threadIdx.x] = t0 * t0 + t1 * t1;
  __syncthreads();
  for (int off = 128; off > 0; off >>= 1) {
    if (threadIdx.x < off) red[threadIdx.x] += red[threadIdx.x + off];
    __syncthreads();
  }
  float var = red[0] / (float)N_GRAPH;
  float scale = rsqrtf(var + BN_EPS) * g[c];
  float bias = bb[c];
  if (r0 < N_GRAPH) Z[(size_t)r0 * HDIM + c] = fmaxf(fmaf(t0, scale, bias), 0.f);
  if (r1 < N_GRAPH) Z[(size_t)r1 * HDIM + c] = fmaxf(fmaf(t1, scale, bias), 0.f);
}

__global__ __launch_bounds__(256) void k_final(const float* __restrict__ H,
                                               const float* __restrict__ w,
                                               const float* __restrict__ b,
                                               float* __restrict__ out) {
  int r = blockIdx.x * 256 + threadIdx.x;
  if (r >= N_GRAPH) return;
  float acc = b[0];
#pragma unroll
  for (int k = 0; k < 64; ++k) acc = fmaf(H[r * HDIM + k], w[k], acc);
  out[r] = acc;
  out[N_GRAPH + r] = acc;
}

// ---------------- launch ----------------

extern "C" void kernel_launch(void* const* d_in, const int* in_sizes, int n_in,
                              void* d_out, int out_size, void* d_ws, size_t ws_size,
                              hipStream_t stream) {
  (void)in_sizes; (void)n_in; (void)out_size; (void)ws_size;
  const float* x0    = (const float*)d_in[0];
  const int*   ei    = (const int*)d_in[1];
  const int*   batch = (const int*)d_in[2];
  const float* preW  = (const float*)d_in[3];
  const float* preb  = (const float*)d_in[4];
  const float* convW = (const float*)d_in[5];
  const float* convb = (const float*)d_in[6];
  const float* ggW   = (const float*)d_in[7];
  const float* ggb   = (const float*)d_in[8];
  const float* lin1W = (const float*)d_in[9];
  const float* lin1b = (const float*)d_in[10];
  const float* lin2W = (const float*)d_in[11];
  const float* lin2b = (const float*)d_in[12];
  const float* lin3W = (const float*)d_in[13];
  const float* lin3b = (const float*)d_in[14];
  const float* lin4W = (const float*)d_in[15];
  const float* lin4b = (const float*)d_in[16];
  const float* bng   = (const float*)d_in[17];
  const float* bnb   = (const float*)d_in[18];
  float* out = (float*)d_out;

  char* ws = (char*)d_ws;
  size_t off = 0;
  auto alloc = [&](size_t bytes) -> void* {
    off = (off + 255) & ~(size_t)255;
    void* p = ws + off;
    off += bytes;
    return p;
  };
  int* deg_in   = (int*)alloc(2ull * N_NODES * 4);  // deg_in, deg_out (memset)
  int* deg_out  = deg_in + N_NODES;
  int* rp_dst   = (int*)alloc((N_NODES + 1) * 4);
  int* rp_src   = (int*)alloc((N_NODES + 1) * 4);
  int* cur_dst  = (int*)alloc((N_NODES + 1) * 4);
  int* cur_src  = (int*)alloc((N_NODES + 1) * 4);
  int* bsum     = (int*)alloc(2 * SC_NBLK * 4);
  int* boff     = (int*)alloc(2 * SC_NBLK * 4);
  int* csr_dst  = (int*)alloc((size_t)N_EDGES * 4);
  int* csr_src  = (int*)alloc((size_t)N_EDGES * 4);
  float* dinv   = (float*)alloc(N_NODES * 4);
  float* x      = (float*)alloc((size_t)N_NODES * HDIM * 4);
  float* x_     = (float*)alloc((size_t)N_NODES * HDIM * 4);
  bf16* Xch     = (bf16*)alloc((size_t)N_NODES * HDIM * 2);
  bf16* xh      = (bf16*)alloc((size_t)N_NODES * HDIM * 2);
  float* hpool  = (float*)alloc(N_GRAPH * HDIM * 4);
  float* epart  = (float*)alloc(NEPART * 4);
  float* mlpA   = (float*)alloc(N_GRAPH * HDIM * 4);
  float* mlpB   = (float*)alloc(N_GRAPH * HDIM * 4);

  hipMemsetAsync(deg_in, 0, 2ull * N_NODES * 4, stream);
  hipMemsetAsync(hpool, 0, N_GRAPH * HDIM * 4, stream);
  hipMemsetAsync(epart, 0, NEPART * 4, stream);

  k_degrees<<<NPARTS * FILL_BPP, 256, 0, stream>>>(ei, deg_in, deg_out);
  {
    dim3 g(SC_NBLK, 2);
    k_scan1<<<g, 256, 0, stream>>>(deg_in, deg_out, rp_dst, rp_src, bsum);
    k_scan2<<<1, 64, 0, stream>>>(bsum, boff, rp_dst, rp_src);
    k_scan3<<<g, 256, 0, stream>>>(boff, rp_dst, rp_src, cur_dst, cur_src, deg_in, dinv);
  }
  k_fill<<<NPARTS * FILL_BPP, 256, 0, stream>>>(ei, cur_dst, cur_src, csr_dst, csr_src);

  k_prelin<<<512, 256, 0, stream>>>(x0, preW, preb, x);

  const int gnode = (N_NODES + 3) / 4;
  for (int l = 0; l < N_LAYERS; ++l) {
    k_agg_gemm<<<1280, 256, 0, stream>>>(x, rp_dst, csr_dst, dinv,
                                         convW + l * HDIM * HDIM, ggW + l * HDIM * HDIM,
                                         convb + l * HDIM, ggb + l * HDIM, x_, Xch);
    k_gate<<<gnode, 256, 0, stream>>>(Xch, x_, rp_src, csr_src, x, xh);
  }

  k_epool<<<gnode, 256, 0, stream>>>(x, xh, rp_src, csr_src, batch, hpool, epart);
  k_esum<<<1, NEPART, 0, stream>>>(epart, out + 2 * N_GRAPH);

  k_mlpbn<<<HDIM, 256, 0, stream>>>(hpool, lin1W, lin1b, bng, bnb, mlpA);
  k_mlpbn<<<HDIM, 256, 0, stream>>>(mlpA, lin2W, lin2b, bng, bnb, mlpB);
  k_mlpbn<<<HDIM, 256, 0, stream>>>(mlpB, lin3W, lin3b, bng, bnb, mlpA);
  k_final<<<(N_GRAPH + 255) / 256, 256, 0, stream>>>(mlpA, lin4W, lin4b, out);
}

// Round 8
// 871.577 us; speedup vs baseline: 1.1606x; 1.1606x over previous
//
#include <hip/hip_runtime.h>
#include <hip/hip_bf16.h>

// G2-GCN fused pipeline for MI355X — round 8.
// vs round 7: DE-FUSE k_agg_gemm. Ledger analysis showed the r4 fusion cost
// ~90us: 32KB LDS + 116 VGPR capped residency at ~16 waves/CU while the
// per-node chain (idx load -> dinv gather -> row gathers -> 64-step GEMM) is
// ~1400cy serial. Split back into r3's VERIFIED kernels:
//   k_agg  : pure gather, 1 wave/node, no LDS, ~30 VGPR -> max TLP.
//   k_gemm2: streaming dual GEMM (LDS weights), bf16 Xch out (r7-verified).
// All other kernels byte-identical to round 7 (passed, absmax 0.0078).

#define N_NODES 50000
#define N_EDGES 800000
#define N_GRAPH 500
#define N_LAYERS 4
#define HDIM 64
#define DDIN 128
#define BN_EPS 1e-5f
#define NEPART 256
#define SC_CHUNK 2048
#define SC_NBLK ((N_NODES + SC_CHUNK - 1) / SC_CHUNK)  // 25
#define NPARTS 8
#define PRNG (N_NODES / NPARTS)  // 6250 exactly
#define FILL_BPP 56              // blocks per partition in partitioned kernels

typedef __hip_bfloat16 bf16;

// ---------------- CSR build ----------------

// XCD-partitioned degree count (verified r6).
__global__ __launch_bounds__(256) void k_degrees(const int* __restrict__ ei,
                                                 int* __restrict__ deg_in,
                                                 int* __restrict__ deg_out) {
  int part = blockIdx.x & (NPARTS - 1);
  int slice = blockIdx.x >> 3;
  int nslice = gridDim.x >> 3;
  int lo = part * PRNG, hi = lo + PRNG;
  int stride = nslice * 256;
  for (int e = slice * 256 + threadIdx.x; e < N_EDGES; e += stride) {
    int s = ei[e], d = ei[N_EDGES + e];
    if (s >= lo && s < hi) atomicAdd(&deg_out[s], 1);
    if (d >= lo && d < hi) atomicAdd(&deg_in[d], 1);
  }
}

// phase 1: per-block local exclusive scan (2048 elems) + block sums.
__global__ __launch_bounds__(256) void k_scan1(const int* __restrict__ deg_in,
                                               const int* __restrict__ deg_out,
                                               int* __restrict__ rp_dst,
                                               int* __restrict__ rp_src,
                                               int* __restrict__ bsum) {
  int arr = blockIdx.y;
  const int* in = arr ? deg_out : deg_in;
  int* out = arr ? rp_src : rp_dst;
  int base = blockIdx.x * SC_CHUNK + threadIdx.x * 8;
  int v[8];
  int s = 0;
#pragma unroll
  for (int j = 0; j < 8; ++j) {
    int ii = base + j;
    v[j] = (ii < N_NODES) ? in[ii] : 0;
    s += v[j];
  }
  __shared__ int sh[256];
  sh[threadIdx.x] = s;
  __syncthreads();
  for (int off = 1; off < 256; off <<= 1) {
    int t = (threadIdx.x >= off) ? sh[threadIdx.x - off] : 0;
    __syncthreads();
    sh[threadIdx.x] += t;
    __syncthreads();
  }
  int run = sh[threadIdx.x] - s;
#pragma unroll
  for (int j = 0; j < 8; ++j) {
    int ii = base + j;
    if (ii < N_NODES) out[ii] = run;
    run += v[j];
  }
  if (threadIdx.x == 255) bsum[arr * SC_NBLK + blockIdx.x] = sh[255];
}

// phase 2: scan the block sums (one wave), set rp[N]=E.
__global__ __launch_bounds__(64) void k_scan2(const int* __restrict__ bsum,
                                              int* __restrict__ boff,
                                              int* __restrict__ rp_dst,
                                              int* __restrict__ rp_src) {
  int lane = threadIdx.x;
  for (int a = 0; a < 2; ++a) {
    int v = (lane < SC_NBLK) ? bsum[a * SC_NBLK + lane] : 0;
    int incl = v;
    for (int off = 1; off < 64; off <<= 1) {
      int t = __shfl_up(incl, off);
      if (lane >= off) incl += t;
    }
    if (lane < SC_NBLK) boff[a * SC_NBLK + lane] = incl - v;
  }
  if (lane == 0) {
    rp_dst[N_NODES] = N_EDGES;
    rp_src[N_NODES] = N_EDGES;
  }
}

// phase 3: add block offsets, write cursor copies; fuse dinv (arr 0).
__global__ __launch_bounds__(256) void k_scan3(const int* __restrict__ boff,
                                               int* __restrict__ rp_dst,
                                               int* __restrict__ rp_src,
                                               int* __restrict__ cur_dst,
                                               int* __restrict__ cur_src,
                                               const int* __restrict__ deg_in,
                                               float* __restrict__ dinv) {
  int arr = blockIdx.y;
  int* rp = arr ? rp_src : rp_dst;
  int* cur = arr ? cur_src : cur_dst;
  int off = boff[arr * SC_NBLK + blockIdx.x];
  int base = blockIdx.x * SC_CHUNK + threadIdx.x * 8;
#pragma unroll
  for (int j = 0; j < 8; ++j) {
    int ii = base + j;
    if (ii < N_NODES) {
      int v = rp[ii] + off;
      rp[ii] = v;
      cur[ii] = v;
      if (arr == 0) dinv[ii] = rsqrtf((float)(deg_in[ii] + 1));  // + self loop
    }
  }
}

// XCD-partitioned fill (verified r6).
__global__ __launch_bounds__(256) void k_fill(const int* __restrict__ ei,
                                              int* __restrict__ cur_dst,
                                              int* __restrict__ cur_src,
                                              int* __restrict__ csr_dst,
                                              int* __restrict__ csr_src) {
  int part = blockIdx.x & (NPARTS - 1);
  int slice = blockIdx.x >> 3;
  int nslice = gridDim.x >> 3;
  int lo = part * PRNG, hi = lo + PRNG;
  int stride = nslice * 256;
  for (int e = slice * 256 + threadIdx.x; e < N_EDGES; e += stride) {
    int s = ei[e], d = ei[N_EDGES + e];
    if (d >= lo && d < hi) {
      int q = atomicAdd(&cur_dst[d], 1);
      csr_dst[q] = s;  // source node for dst-gather
    }
    if (s >= lo && s < hi) {
      int q = atomicAdd(&cur_src[s], 1);
      csr_src[q] = d;  // dest node for src-gather
    }
  }
}

// ---------------- dense kernels ----------------

__global__ __launch_bounds__(256) void k_prelin(const float* __restrict__ x0,
                                                const float* __restrict__ W,
                                                const float* __restrict__ b,
                                                float* __restrict__ x) {
  __shared__ float Ws[DDIN * HDIM];  // 32 KB
  for (int t = threadIdx.x; t < DDIN * HDIM; t += 256) Ws[t] = W[t];
  __syncthreads();
  int wave = threadIdx.x >> 6, lane = threadIdx.x & 63;
  float bias = b[lane];
  int stride = gridDim.x * 4;
  for (int i = blockIdx.x * 4 + wave; i < N_NODES; i += stride) {
    const float* xr = x0 + (size_t)i * DDIN;
    float xl0 = xr[lane], xl1 = xr[64 + lane];
    float acc = bias;
#pragma unroll
    for (int k = 0; k < 64; ++k) acc = fmaf(__shfl(xl0, k), Ws[k * 64 + lane], acc);
#pragma unroll
    for (int k = 0; k < 64; ++k) acc = fmaf(__shfl(xl1, k), Ws[(64 + k) * 64 + lane], acc);
    x[(size_t)i * HDIM + lane] = fmaxf(acc, 0.f);
  }
}

// ---------------- pure gather (one wave per node, r3-verified structure) -----
// aggb[i] = dinv[i] * (x[i]*dinv[i] + sum_{s in in(i)} x[s]*dinv[s])
__global__ __launch_bounds__(256) void k_agg(const float* __restrict__ x,
                                             const int* __restrict__ rp,
                                             const int* __restrict__ csr,
                                             const float* __restrict__ dinv,
                                             float* __restrict__ aggb) {
  int i = (blockIdx.x * 256 + threadIdx.x) >> 6;
  int lane = threadIdx.x & 63;
  if (i >= N_NODES) return;
  int e0 = rp[i], e1 = rp[i + 1];
  float di = dinv[i];
  size_t li = (size_t)i * HDIM + lane;
  float a0 = x[li] * di, a1 = 0.f, a2 = 0.f, a3 = 0.f;  // self loop in a0
  for (int base = e0; base < e1; base += 64) {
    int m = e1 - base;
    if (m > 64) m = 64;
    int idx = csr[base + (lane < m ? lane : 0)];
    float dv = dinv[idx];
    int k = 0;
    for (; k + 8 <= m; k += 8) {
      int s0 = __shfl(idx, k), s1 = __shfl(idx, k + 1), s2 = __shfl(idx, k + 2),
          s3 = __shfl(idx, k + 3), s4 = __shfl(idx, k + 4), s5 = __shfl(idx, k + 5),
          s6 = __shfl(idx, k + 6), s7 = __shfl(idx, k + 7);
      float w0 = __shfl(dv, k), w1 = __shfl(dv, k + 1), w2 = __shfl(dv, k + 2),
            w3 = __shfl(dv, k + 3), w4 = __shfl(dv, k + 4), w5 = __shfl(dv, k + 5),
            w6 = __shfl(dv, k + 6), w7 = __shfl(dv, k + 7);
      float v0 = x[(size_t)s0 * HDIM + lane], v1 = x[(size_t)s1 * HDIM + lane];
      float v2 = x[(size_t)s2 * HDIM + lane], v3 = x[(size_t)s3 * HDIM + lane];
      float v4 = x[(size_t)s4 * HDIM + lane], v5 = x[(size_t)s5 * HDIM + lane];
      float v6 = x[(size_t)s6 * HDIM + lane], v7 = x[(size_t)s7 * HDIM + lane];
      a0 = fmaf(v0, w0, a0);
      a1 = fmaf(v1, w1, a1);
      a2 = fmaf(v2, w2, a2);
      a3 = fmaf(v3, w3, a3);
      a0 = fmaf(v4, w4, a0);
      a1 = fmaf(v5, w5, a1);
      a2 = fmaf(v6, w6, a2);
      a3 = fmaf(v7, w7, a3);
    }
    for (; k < m; ++k) {
      int s = __shfl(idx, k);
      float w = __shfl(dv, k);
      a0 = fmaf(x[(size_t)s * HDIM + lane], w, a0);
    }
  }
  aggb[li] = (a0 + a1 + a2 + a3) * di;
}

// ---------------- streaming dual GEMM (r3-verified, bf16 Xch out) -----------
// x_ = relu(agg@W1+b1) [fp32], Xch = relu(agg@W2+b2) [bf16, gate input only].
__global__ __launch_bounds__(256) void k_gemm2(const float* __restrict__ agg,
                                               const float* __restrict__ W1,
                                               const float* __restrict__ W2,
                                               const float* __restrict__ b1,
                                               const float* __restrict__ b2,
                                               float* __restrict__ x_,
                                               bf16* __restrict__ Xch) {
  __shared__ float W1s[HDIM * HDIM], W2s[HDIM * HDIM];
  for (int t = threadIdx.x; t < HDIM * HDIM; t += 256) {
    W1s[t] = W1[t];
    W2s[t] = W2[t];
  }
  __syncthreads();
  int wave = threadIdx.x >> 6, lane = threadIdx.x & 63;
  float bb1 = b1[lane], bb2 = b2[lane];
  int stride = gridDim.x * 4;
  for (int i = blockIdx.x * 4 + wave; i < N_NODES; i += stride) {
    size_t li = (size_t)i * HDIM + lane;
    float xl = agg[li];
    float r1 = 0.f, r2 = 0.f;
#pragma unroll
    for (int k = 0; k < 64; ++k) {
      float xv = __shfl(xl, k);
      r1 = fmaf(xv, W1s[k * 64 + lane], r1);
      r2 = fmaf(xv, W2s[k * 64 + lane], r2);
    }
    x_[li] = fmaxf(r1 + bb1, 0.f);
    Xch[li] = __float2bfloat16(fmaxf(r2 + bb2, 0.f));
  }
}

// tau = tanh(mean_over_out_edges (Xc[i]-Xc[d])^2) on bf16 rows;
// x = (1-tau)*x + tau*x_ ; also emit bf16 copy of new x for the energy pass.
__global__ __launch_bounds__(256) void k_gate(const bf16* __restrict__ Xch,
                                              const float* __restrict__ x_,
                                              const int* __restrict__ rp,
                                              const int* __restrict__ csr,
                                              float* __restrict__ x,
                                              bf16* __restrict__ xh) {
  int i = (blockIdx.x * 256 + threadIdx.x) >> 6;
  int lane = threadIdx.x & 63;
  if (i >= N_NODES) return;
  int e0 = rp[i], e1 = rp[i + 1];
  float xi = __bfloat162float(Xch[(size_t)i * HDIM + lane]);
  float a0 = 0.f, a1 = 0.f, a2 = 0.f, a3 = 0.f;
  for (int base = e0; base < e1; base += 64) {
    int m = e1 - base;
    if (m > 64) m = 64;
    int idx = csr[base + (lane < m ? lane : 0)];
    int k = 0;
    for (; k + 8 <= m; k += 8) {
      int s0 = __shfl(idx, k), s1 = __shfl(idx, k + 1), s2 = __shfl(idx, k + 2),
          s3 = __shfl(idx, k + 3), s4 = __shfl(idx, k + 4), s5 = __shfl(idx, k + 5),
          s6 = __shfl(idx, k + 6), s7 = __shfl(idx, k + 7);
      float v0 = __bfloat162float(Xch[(size_t)s0 * HDIM + lane]);
      float v1 = __bfloat162float(Xch[(size_t)s1 * HDIM + lane]);
      float v2 = __bfloat162float(Xch[(size_t)s2 * HDIM + lane]);
      float v3 = __bfloat162float(Xch[(size_t)s3 * HDIM + lane]);
      float v4 = __bfloat162float(Xch[(size_t)s4 * HDIM + lane]);
      float v5 = __bfloat162float(Xch[(size_t)s5 * HDIM + lane]);
      float v6 = __bfloat162float(Xch[(size_t)s6 * HDIM + lane]);
      float v7 = __bfloat162float(Xch[(size_t)s7 * HDIM + lane]);
      float t0 = xi - v0, t1 = xi - v1, t2 = xi - v2, t3 = xi - v3;
      float t4 = xi - v4, t5 = xi - v5, t6 = xi - v6, t7 = xi - v7;
      a0 = fmaf(t0, t0, a0);
      a1 = fmaf(t1, t1, a1);
      a2 = fmaf(t2, t2, a2);
      a3 = fmaf(t3, t3, a3);
      a0 = fmaf(t4, t4, a0);
      a1 = fmaf(t5, t5, a1);
      a2 = fmaf(t6, t6, a2);
      a3 = fmaf(t7, t7, a3);
    }
    for (; k < m; ++k) {
      int d = __shfl(idx, k);
      float t = xi - __bfloat162float(Xch[(size_t)d * HDIM + lane]);
      a0 = fmaf(t, t, a0);
    }
  }
  int cnt = e1 - e0;
  float tau = tanhf((a0 + a1 + a2 + a3) / (float)(cnt > 0 ? cnt : 1));
  size_t idx = (size_t)i * HDIM + lane;
  float xn = (1.f - tau) * x[idx] + tau * x_[idx];
  x[idx] = xn;
  xh[idx] = __float2bfloat16(xn);
}

// energy partials (grouped by src, bf16 rows) + global add pool (fp32), fused.
__global__ __launch_bounds__(256) void k_epool(const float* __restrict__ x,
                                               const bf16* __restrict__ xh,
                                               const int* __restrict__ rp,
                                               const int* __restrict__ csr,
                                               const int* __restrict__ batch,
                                               float* __restrict__ hpool,
                                               float* __restrict__ epart) {
  int i = (blockIdx.x * 256 + threadIdx.x) >> 6;
  int lane = threadIdx.x & 63;
  if (i >= N_NODES) return;
  size_t li = (size_t)i * HDIM + lane;
  float xi = __bfloat162float(xh[li]);  // symmetric rounding vs gathered rows
  int e0 = rp[i], e1 = rp[i + 1];
  float a0 = 0.f, a1 = 0.f, a2 = 0.f, a3 = 0.f;
  for (int base = e0; base < e1; base += 64) {
    int m = e1 - base;
    if (m > 64) m = 64;
    int idx = csr[base + (lane < m ? lane : 0)];
    int k = 0;
    for (; k + 8 <= m; k += 8) {
      int s0 = __shfl(idx, k), s1 = __shfl(idx, k + 1), s2 = __shfl(idx, k + 2),
          s3 = __shfl(idx, k + 3), s4 = __shfl(idx, k + 4), s5 = __shfl(idx, k + 5),
          s6 = __shfl(idx, k + 6), s7 = __shfl(idx, k + 7);
      float v0 = __bfloat162float(xh[(size_t)s0 * HDIM + lane]);
      float v1 = __bfloat162float(xh[(size_t)s1 * HDIM + lane]);
      float v2 = __bfloat162float(xh[(size_t)s2 * HDIM + lane]);
      float v3 = __bfloat162float(xh[(size_t)s3 * HDIM + lane]);
      float v4 = __bfloat162float(xh[(size_t)s4 * HDIM + lane]);
      float v5 = __bfloat162float(xh[(size_t)s5 * HDIM + lane]);
      float v6 = __bfloat162float(xh[(size_t)s6 * HDIM + lane]);
      float v7 = __bfloat162float(xh[(size_t)s7 * HDIM + lane]);
      float t0 = xi - v0, t1 = xi - v1, t2 = xi - v2, t3 = xi - v3;
      float t4 = xi - v4, t5 = xi - v5, t6 = xi - v6, t7 = xi - v7;
      a0 = fmaf(t0, t0, a0);
      a1 = fmaf(t1, t1, a1);
      a2 = fmaf(t2, t2, a2);
      a3 = fmaf(t3, t3, a3);
      a0 = fmaf(t4, t4, a0);
      a1 = fmaf(t5, t5, a1);
      a2 = fmaf(t6, t6, a2);
      a3 = fmaf(t7, t7, a3);
    }
    for (; k < m; ++k) {
      int d = __shfl(idx, k);
      float t = xi - __bfloat162float(xh[(size_t)d * HDIM + lane]);
      a0 = fmaf(t, t, a0);
    }
  }
  int g = batch[i];  // wave-uniform
  atomicAdd(&hpool[g * HDIM + lane], x[li]);  // exact fp32 pool
  float acc = a0 + a1 + a2 + a3;
  acc += __shfl_down(acc, 32);
  acc += __shfl_down(acc, 16);
  acc += __shfl_down(acc, 8);
  acc += __shfl_down(acc, 4);
  acc += __shfl_down(acc, 2);
  acc += __shfl_down(acc, 1);
  if (lane == 0) atomicAdd(&epart[i & (NEPART - 1)], acc);
}

__global__ __launch_bounds__(256) void k_esum(const float* __restrict__ epart,
                                              float* __restrict__ out_e) {
  __shared__ float sh[NEPART];
  int t = threadIdx.x;
  sh[t] = epart[t];
  __syncthreads();
  for (int off = NEPART / 2; off > 0; off >>= 1) {
    if (t < off) sh[t] += sh[t + off];
    __syncthreads();
  }
  if (t == 0) out_e[0] = 0.5f * sh[0];
}

// ---------------- readout MLP (fused GEMM + BN + relu, one block per column) --

__global__ __launch_bounds__(256) void k_mlpbn(const float* __restrict__ Hin,
                                               const float* __restrict__ W,
                                               const float* __restrict__ b,
                                               const float* __restrict__ g,
                                               const float* __restrict__ bb,
                                               float* __restrict__ Z) {
  int c = blockIdx.x;
  __shared__ float Wc[HDIM];
  __shared__ float red[256];
  if (threadIdx.x < HDIM) Wc[threadIdx.x] = W[threadIdx.x * HDIM + c];
  __syncthreads();
  int r0 = threadIdx.x, r1 = threadIdx.x + 256;
  float bc = b[c];
  float d0 = bc, d1 = bc;
  if (r0 < N_GRAPH) {
    const float* h = Hin + (size_t)r0 * HDIM;
#pragma unroll
    for (int k = 0; k < HDIM; ++k) d0 = fmaf(h[k], Wc[k], d0);
  }
  if (r1 < N_GRAPH) {
    const float* h = Hin + (size_t)r1 * HDIM;
#pragma unroll
    for (int k = 0; k < HDIM; ++k) d1 = fmaf(h[k], Wc[k], d1);
  }
  red[threadIdx.x] = (r0 < N_GRAPH ? d0 : 0.f) + (r1 < N_GRAPH ? d1 : 0.f);
  __syncthreads();
  for (int off = 128; off > 0; off >>= 1) {
    if (threadIdx.x < off) red[threadIdx.x] += red[threadIdx.x + off];
    __syncthreads();
  }
  float mean = red[0] / (float)N_GRAPH;
  __syncthreads();
  float t0 = (r0 < N_GRAPH) ? d0 - mean : 0.f;
  float t1 = (r1 < N_GRAPH) ? d1 - mean : 0.f;
  red[threadIdx.x] = t0 * t0 + t1 * t1;
  __syncthreads();
  for (int off = 128; off > 0; off >>= 1) {
    if (threadIdx.x < off) red[threadIdx.x] += red[threadIdx.x + off];
    __syncthreads();
  }
  float var = red[0] / (float)N_GRAPH;
  float scale = rsqrtf(var + BN_EPS) * g[c];
  float bias = bb[c];
  if (r0 < N_GRAPH) Z[(size_t)r0 * HDIM + c] = fmaxf(fmaf(t0, scale, bias), 0.f);
  if (r1 < N_GRAPH) Z[(size_t)r1 * HDIM + c] = fmaxf(fmaf(t1, scale, bias), 0.f);
}

__global__ __launch_bounds__(256) void k_final(const float* __restrict__ H,
                                               const float* __restrict__ w,
                                               const float* __restrict__ b,
                                               float* __restrict__ out) {
  int r = blockIdx.x * 256 + threadIdx.x;
  if (r >= N_GRAPH) return;
  float acc = b[0];
#pragma unroll
  for (int k = 0; k < 64; ++k) acc = fmaf(H[r * HDIM + k], w[k], acc);
  out[r] = acc;
  out[N_GRAPH + r] = acc;
}

// ---------------- launch ----------------

extern "C" void kernel_launch(void* const* d_in, const int* in_sizes, int n_in,
                              void* d_out, int out_size, void* d_ws, size_t ws_size,
                              hipStream_t stream) {
  (void)in_sizes; (void)n_in; (void)out_size; (void)ws_size;
  const float* x0    = (const float*)d_in[0];
  const int*   ei    = (const int*)d_in[1];
  const int*   batch = (const int*)d_in[2];
  const float* preW  = (const float*)d_in[3];
  const float* preb  = (const float*)d_in[4];
  const float* convW = (const float*)d_in[5];
  const float* convb = (const float*)d_in[6];
  const float* ggW   = (const float*)d_in[7];
  const float* ggb   = (const float*)d_in[8];
  const float* lin1W = (const float*)d_in[9];
  const float* lin1b = (const float*)d_in[10];
  const float* lin2W = (const float*)d_in[11];
  const float* lin2b = (const float*)d_in[12];
  const float* lin3W = (const float*)d_in[13];
  const float* lin3b = (const float*)d_in[14];
  const float* lin4W = (const float*)d_in[15];
  const float* lin4b = (const float*)d_in[16];
  const float* bng   = (const float*)d_in[17];
  const float* bnb   = (const float*)d_in[18];
  float* out = (float*)d_out;

  char* ws = (char*)d_ws;
  size_t off = 0;
  auto alloc = [&](size_t bytes) -> void* {
    off = (off + 255) & ~(size_t)255;
    void* p = ws + off;
    off += bytes;
    return p;
  };
  int* deg_in   = (int*)alloc(2ull * N_NODES * 4);  // deg_in, deg_out (memset)
  int* deg_out  = deg_in + N_NODES;
  int* rp_dst   = (int*)alloc((N_NODES + 1) * 4);
  int* rp_src   = (int*)alloc((N_NODES + 1) * 4);
  int* cur_dst  = (int*)alloc((N_NODES + 1) * 4);
  int* cur_src  = (int*)alloc((N_NODES + 1) * 4);
  int* bsum     = (int*)alloc(2 * SC_NBLK * 4);
  int* boff     = (int*)alloc(2 * SC_NBLK * 4);
  int* csr_dst  = (int*)alloc((size_t)N_EDGES * 4);
  int* csr_src  = (int*)alloc((size_t)N_EDGES * 4);
  float* dinv   = (float*)alloc(N_NODES * 4);
  float* x      = (float*)alloc((size_t)N_NODES * HDIM * 4);
  float* aggb   = (float*)alloc((size_t)N_NODES * HDIM * 4);
  float* x_     = (float*)alloc((size_t)N_NODES * HDIM * 4);
  bf16* Xch     = (bf16*)alloc((size_t)N_NODES * HDIM * 2);
  bf16* xh      = (bf16*)alloc((size_t)N_NODES * HDIM * 2);
  float* hpool  = (float*)alloc(N_GRAPH * HDIM * 4);
  float* epart  = (float*)alloc(NEPART * 4);
  float* mlpA   = (float*)alloc(N_GRAPH * HDIM * 4);
  float* mlpB   = (float*)alloc(N_GRAPH * HDIM * 4);

  hipMemsetAsync(deg_in, 0, 2ull * N_NODES * 4, stream);
  hipMemsetAsync(hpool, 0, N_GRAPH * HDIM * 4, stream);
  hipMemsetAsync(epart, 0, NEPART * 4, stream);

  k_degrees<<<NPARTS * FILL_BPP, 256, 0, stream>>>(ei, deg_in, deg_out);
  {
    dim3 g(SC_NBLK, 2);
    k_scan1<<<g, 256, 0, stream>>>(deg_in, deg_out, rp_dst, rp_src, bsum);
    k_scan2<<<1, 64, 0, stream>>>(bsum, boff, rp_dst, rp_src);
    k_scan3<<<g, 256, 0, stream>>>(boff, rp_dst, rp_src, cur_dst, cur_src, deg_in, dinv);
  }
  k_fill<<<NPARTS * FILL_BPP, 256, 0, stream>>>(ei, cur_dst, cur_src, csr_dst, csr_src);

  k_prelin<<<512, 256, 0, stream>>>(x0, preW, preb, x);

  const int gnode = (N_NODES + 3) / 4;
  for (int l = 0; l < N_LAYERS; ++l) {
    k_agg<<<gnode, 256, 0, stream>>>(x, rp_dst, csr_dst, dinv, aggb);
    k_gemm2<<<1024, 256, 0, stream>>>(aggb, convW + l * HDIM * HDIM, ggW + l * HDIM * HDIM,
                                      convb + l * HDIM, ggb + l * HDIM, x_, Xch);
    k_gate<<<gnode, 256, 0, stream>>>(Xch, x_, rp_src, csr_src, x, xh);
  }

  k_epool<<<gnode, 256, 0, stream>>>(x, xh, rp_src, csr_src, batch, hpool, epart);
  k_esum<<<1, NEPART, 0, stream>>>(epart, out + 2 * N_GRAPH);

  k_mlpbn<<<HDIM, 256, 0, stream>>>(hpool, lin1W, lin1b, bng, bnb, mlpA);
  k_mlpbn<<<HDIM, 256, 0, stream>>>(mlpA, lin2W, lin2b, bng, bnb, mlpB);
  k_mlpbn<<<HDIM, 256, 0, stream>>>(mlpB, lin3W, lin3b, bng, bnb, mlpA);
  k_final<<<(N_GRAPH + 255) / 256, 256, 0, stream>>>(mlpA, lin4W, lin4b, out);
}